// Round 3
// baseline (294.301 us; speedup 1.0000x reference)
//
#include <hip/hip_runtime.h>

// SSIM fused, round 8: make the 128-VGPR budget COMPILER-PROOF.
//  - Round 7 history: identical source compiled twice on two containers:
//      build A: VGPR=128 SGPR=84  -> 53.4 us, WRITE_SIZE=25 KB (no spill),
//               HBM 62%, VALUBusy 83%, FETCH 259 MB = exactly one pass.
//      build B: VGPR=64  SGPR=112 -> 138.6 us, WRITE_SIZE=88.9 MB (ring
//               spilled to scratch again).
//    SGPR 84 vs 112 on unchanged source == different compiler build; build
//    B's allocator treats amdgpu_waves_per_eu(4,4) as a soft hint and aims
//    for the 8-waves/EU (64-reg) step, re-spilling the 70-float ring.
//  - Fix: pin the budget directly with amdgpu_num_vgpr(128) (hard allocator
//    constraint), keep waves_per_eu(4,4) as a secondary hint. Live state is
//    ~112 VGPRs -> fits 128 with slack; grid (1024 blocks = 4/CU = 4
//    waves/EU) already saturates exactly that occupancy.
// Geometry: 16 x 1 x 1080 x 1920 fp32; VALID 7x7 -> 16 x 1074 x 1914.

constexpr int W_IN = 1920, H_IN = 1080;
constexpr int WOUT = W_IN - 6;    // 1914
constexpr int HOUT = H_IN - 6;    // 1074
constexpr int NBATCH = 16;
constexpr int WCOLS = 122;        // productive cols per wave (61 lanes x 2)
constexpr int TW = 4 * WCOLS;     // 488 cols per block
constexpr int TH = 71;            // output rows per y-tile (NITER = 77 = 7*11)
constexpr int NBX = 4, NBY = 16;  // 4*488>=1914(+pad), 16*71>=1074
constexpr int NBLK = NBX * NBY * NBATCH;  // 1024 = exactly 4 per CU

constexpr float C1f = 6.5025f;    // (0.01*255)^2
constexpr float C2f = 58.5225f;   // (0.03*255)^2
constexpr float INV49 = 1.0f / 49.0f;

__device__ __forceinline__ float bperm(int addr, float v) {
  return __int_as_float(__builtin_amdgcn_ds_bpermute(addr, __float_as_int(v)));
}

__global__ __attribute__((amdgpu_flat_work_group_size(256, 256),
                          amdgpu_waves_per_eu(4, 4),
                          amdgpu_num_vgpr(128)))
void ssim_kernel(const float* __restrict__ img1, const float* __restrict__ img2,
                 double* __restrict__ partial) {
  const int t = threadIdx.x;
  const int lane = t & 63;
  const int xw = blockIdx.x * TW + (t >> 6) * WCOLS;  // wave col base
  const int y0 = blockIdx.y * TH;
  const size_t ib = (size_t)blockIdx.z * (size_t)(H_IN * W_IN);
  const float* __restrict__ p1 = img1 + ib;
  const float* __restrict__ p2 = img2 + ib;

  // gcol is always even (xw even, 2*lane even) -> the W_IN-2 clamp can only
  // hit non-productive/halo-irrelevant lanes (parity argument: the last
  // productive window, col 1913, is always a c1, whose c0+7 halo float is
  // lane+3's .y at cols (1918,1919) -> unclamped).
  const int gcol = min(xw + 2 * lane, W_IN - 2);  // clamped, 8B-aligned
  const int up1 = ((lane + 1) & 63) << 2;         // bpermute byte addrs
  const int up2 = ((lane + 2) & 63) << 2;
  const int up3 = ((lane + 3) & 63) << 2;
  const bool lv = lane < 61;
  const bool m0 = lv && (xw + 2 * lane + 0 < WOUT);
  const bool m1 = lv && (xw + 2 * lane + 1 < WOUT);

  // thread-private rowsum ring: 5 quantities x 2 cols x 7 slots (named)
#define DECLR(Q, C)                                                          \
  float R##Q##_##C##_0 = 0.f, R##Q##_##C##_1 = 0.f, R##Q##_##C##_2 = 0.f,    \
        R##Q##_##C##_3 = 0.f, R##Q##_##C##_4 = 0.f, R##Q##_##C##_5 = 0.f,    \
        R##Q##_##C##_6 = 0.f;
  DECLR(1, 0) DECLR(1, 1)
  DECLR(2, 0) DECLR(2, 1)
  DECLR(3, 0) DECLR(3, 1)   // 3 = a*a
  DECLR(4, 0) DECLR(4, 1)   // 4 = b*b
  DECLR(5, 0) DECLR(5, 1)   // 5 = a*b
#undef DECLR
#define DECLV(Q) float V##Q##_0 = 0.f, V##Q##_1 = 0.f;
  DECLV(1) DECLV(2) DECLV(3) DECLV(4) DECLV(5)
#undef DECLV

  float accv = 0.f;

  // prologue: row y0 -> A registers (y0 <= 1065, no clamp needed)
  float2 Aa = *(const float2*)(p1 + (size_t)y0 * W_IN + gcol);
  float2 Ab = *(const float2*)(p2 + (size_t)y0 * W_IN + gcol);
  float2 Ba, Bb;
  int gyn = y0 + 1;   // next input row to load (block-uniform -> SALU)
  int oy = y0;        // output row counter

#define QC(Q, C, J)                                                         \
  { V##Q##_##C += s - R##Q##_##C##_##J; R##Q##_##C##_##J = s; }

#define EPI1(VA, VB, VAA, VBB, VAB, MASK)                                   \
  {                                                                         \
    const float mu1 = (VA) * INV49, mu2 = (VB) * INV49;                     \
    const float mu1s = mu1 * mu1, mu2s = mu2 * mu2, mu12 = mu1 * mu2;       \
    const float sg1 = fmaf((VAA), INV49, -mu1s);                            \
    const float sg2 = fmaf((VBB), INV49, -mu2s);                            \
    const float sg12 = fmaf((VAB), INV49, -mu12);                           \
    const float v1 = fmaf(2.f, sg12, C2f);                                  \
    const float v2 = sg1 + sg2 + C2f;                                       \
    const float num = fmaf(2.f, mu12, C1f) * v1;                            \
    const float den = (mu1s + mu2s + C1f) * v2;                             \
    const float ss = num * __builtin_amdgcn_rcpf(den);                      \
    accv += (MASK) ? ss : 0.f;                                              \
  }

  // One input row k: CA holds row k (both imgs); NA receives row k+1
  // (issued first for latency cover); halo via bpermute; ring-slide; EPI.
  // Window cols for c0: CAa.x(c0) CAa.y(+1) a1x(+2) a1y(+3) a2x(+4)
  //                     a2y(+5) a3x(+6);  c1 slides: -CAa.x +a3y(+7).
#define STEP(J, CAa, CAb, NAa, NAb, DO_EPI)                                 \
  {                                                                         \
    NAa = *(const float2*)(p1 + (size_t)gyn * W_IN + gcol);                 \
    NAb = *(const float2*)(p2 + (size_t)gyn * W_IN + gcol);                 \
    gyn = min(gyn + 1, H_IN - 1);                                           \
    const float a1x = bperm(up1, CAa.x), a1y = bperm(up1, CAa.y);           \
    const float a2x = bperm(up2, CAa.x), a2y = bperm(up2, CAa.y);           \
    const float a3x = bperm(up3, CAa.x), a3y = bperm(up3, CAa.y);           \
    const float b1x = bperm(up1, CAb.x), b1y = bperm(up1, CAb.y);           \
    const float b2x = bperm(up2, CAb.x), b2y = bperm(up2, CAb.y);           \
    const float b3x = bperm(up3, CAb.x), b3y = bperm(up3, CAb.y);           \
    float s;                                                                \
    s = ((CAa.x + CAa.y) + (a1x + a1y)) + ((a2x + a2y) + a3x);              \
    QC(1, 0, J)                                                             \
    s = s - CAa.x + a3y;  QC(1, 1, J)                                       \
    s = ((CAb.x + CAb.y) + (b1x + b1y)) + ((b2x + b2y) + b3x);              \
    QC(2, 0, J)                                                             \
    s = s - CAb.x + b3y;  QC(2, 1, J)                                       \
    s = CAa.x * CAa.x;                                                      \
    s = fmaf(CAa.y, CAa.y, s); s = fmaf(a1x, a1x, s);                       \
    s = fmaf(a1y, a1y, s); s = fmaf(a2x, a2x, s);                           \
    s = fmaf(a2y, a2y, s); s = fmaf(a3x, a3x, s);                           \
    QC(3, 0, J)                                                             \
    s = fmaf(-CAa.x, CAa.x, fmaf(a3y, a3y, s));  QC(3, 1, J)                \
    s = CAb.x * CAb.x;                                                      \
    s = fmaf(CAb.y, CAb.y, s); s = fmaf(b1x, b1x, s);                       \
    s = fmaf(b1y, b1y, s); s = fmaf(b2x, b2x, s);                           \
    s = fmaf(b2y, b2y, s); s = fmaf(b3x, b3x, s);                           \
    QC(4, 0, J)                                                             \
    s = fmaf(-CAb.x, CAb.x, fmaf(b3y, b3y, s));  QC(4, 1, J)                \
    s = CAa.x * CAb.x;                                                      \
    s = fmaf(CAa.y, CAb.y, s); s = fmaf(a1x, b1x, s);                       \
    s = fmaf(a1y, b1y, s); s = fmaf(a2x, b2x, s);                           \
    s = fmaf(a2y, b2y, s); s = fmaf(a3x, b3x, s);                           \
    QC(5, 0, J)                                                             \
    s = fmaf(-CAa.x, CAb.x, fmaf(a3y, b3y, s));  QC(5, 1, J)                \
    if (DO_EPI) {                                                           \
      if (oy < HOUT) {                                                      \
        EPI1(V1_0, V2_0, V3_0, V4_0, V5_0, m0)                              \
        EPI1(V1_1, V2_1, V3_1, V4_1, V5_1, m1)                              \
      }                                                                     \
      ++oy;                                                                 \
    }                                                                       \
  }

  // warm-up group: rows 0..6 (row k consumed from A if k even, B if odd)
  STEP(0, Aa, Ab, Ba, Bb, false)
  STEP(1, Ba, Bb, Aa, Ab, false)
  STEP(2, Aa, Ab, Ba, Bb, false)
  STEP(3, Ba, Bb, Aa, Ab, false)
  STEP(4, Aa, Ab, Ba, Bb, false)
  STEP(5, Ba, Bb, Aa, Ab, false)
  STEP(6, Aa, Ab, Ba, Bb, true)
  // 5 x (odd-start group + even-start group): rows 7..76
  for (int gp = 0; gp < 5; ++gp) {
    STEP(0, Ba, Bb, Aa, Ab, true)
    STEP(1, Aa, Ab, Ba, Bb, true)
    STEP(2, Ba, Bb, Aa, Ab, true)
    STEP(3, Aa, Ab, Ba, Bb, true)
    STEP(4, Ba, Bb, Aa, Ab, true)
    STEP(5, Aa, Ab, Ba, Bb, true)
    STEP(6, Ba, Bb, Aa, Ab, true)
    STEP(0, Aa, Ab, Ba, Bb, true)
    STEP(1, Ba, Bb, Aa, Ab, true)
    STEP(2, Aa, Ab, Ba, Bb, true)
    STEP(3, Ba, Bb, Aa, Ab, true)
    STEP(4, Aa, Ab, Ba, Bb, true)
    STEP(5, Ba, Bb, Aa, Ab, true)
    STEP(6, Aa, Ab, Ba, Bb, true)
  }
#undef STEP
#undef QC
#undef EPI1

  // block reduction: 64-wide shuffle -> LDS -> one double per block
  __shared__ float wsum[4];
#pragma unroll
  for (int off = 32; off > 0; off >>= 1) accv += __shfl_down(accv, off);
  if ((t & 63) == 0) wsum[t >> 6] = accv;
  __syncthreads();
  if (t == 0) {
    const int bid = blockIdx.x + NBX * (blockIdx.y + NBY * blockIdx.z);
    partial[bid] = (double)wsum[0] + (double)wsum[1] +
                   (double)wsum[2] + (double)wsum[3];
  }
}

__global__ __launch_bounds__(256)
void finalize_kernel(const double* __restrict__ partial,
                     float* __restrict__ out) {
  const int tid = threadIdx.x;
  double s = 0.0;
  for (int i = tid; i < NBLK; i += 256) s += partial[i];
#pragma unroll
  for (int off = 32; off > 0; off >>= 1) s += __shfl_down(s, off);
  __shared__ double ws[4];
  if ((tid & 63) == 0) ws[tid >> 6] = s;
  __syncthreads();
  if (tid == 0) {
    const double tot = ws[0] + ws[1] + ws[2] + ws[3];
    out[0] = (float)(tot / ((double)NBATCH * (double)HOUT * (double)WOUT));
  }
}

extern "C" void kernel_launch(void* const* d_in, const int* in_sizes, int n_in,
                              void* d_out, int out_size, void* d_ws, size_t ws_size,
                              hipStream_t stream) {
  const float* img1 = (const float*)d_in[0];
  const float* img2 = (const float*)d_in[1];
  // d_in[2] is the uniform 1/49 window -- baked into INV49.
  double* partial = (double*)d_ws;  // NBLK doubles, every slot written
  dim3 grid(NBX, NBY, NBATCH);      // 4 x 16 x 16 = 1024 blocks
  hipLaunchKernelGGL(ssim_kernel, grid, dim3(256), 0, stream, img1, img2,
                     partial);
  hipLaunchKernelGGL(finalize_kernel, dim3(1), dim3(256), 0, stream, partial,
                     (float*)d_out);
}

// Round 4
// 293.143 us; speedup vs baseline: 1.0039x; 1.0039x over previous
//
#include <hip/hip_runtime.h>

// SSIM fused, round 9: clamp the allocator with an LDS occupancy anchor.
//  - Round 7/8 history, same source, two compiler builds:
//      good build: VGPR=128 SGPR=84  -> 53.4 us, WRITE_SIZE=25 KB, HBM 62%,
//                  VALUBusy 83%, FETCH 259 MB = one clean input pass.
//      bad build:  VGPR=64  SGPR=112 -> 119-138 us, WRITE_SIZE=88 MB (the
//                  70-float ring spilled to scratch). waves_per_eu(4,4) AND
//                  amdgpu_num_vgpr(128) both provably IGNORED (identical
//                  allocation with and without num_vgpr).
//  - Fix that no build can ignore: static LDS of 36 KiB/block. Occupancy
//    bound from LDS = floor(160 KiB / 36 KiB) = 4 blocks/CU = 4 waves/EU.
//    The allocator's occupancy target is min(heuristic, LDS bound), so its
//    8-waves/EU (64-reg) target collapses to 4 waves/EU -> 128-reg budget.
//    Grid is 1024 = 4 blocks/CU: the pad caps occupancy at the value the
//    kernel already runs at, so on the good build it is a strict no-op.
//  - Live state ~112 VGPRs fits 128 with slack; no spills.
// Geometry: 16 x 1 x 1080 x 1920 fp32; VALID 7x7 -> 16 x 1074 x 1914.

constexpr int W_IN = 1920, H_IN = 1080;
constexpr int WOUT = W_IN - 6;    // 1914
constexpr int HOUT = H_IN - 6;    // 1074
constexpr int NBATCH = 16;
constexpr int WCOLS = 122;        // productive cols per wave (61 lanes x 2)
constexpr int TW = 4 * WCOLS;     // 488 cols per block
constexpr int TH = 71;            // output rows per y-tile (NITER = 77 = 7*11)
constexpr int NBX = 4, NBY = 16;  // 4*488>=1914(+pad), 16*71>=1074
constexpr int NBLK = NBX * NBY * NBATCH;  // 1024 = exactly 4 per CU

// LDS occupancy anchor: 9216 floats = 36864 B. floor(163840/36864) = 4
// blocks/CU -> hard 4-waves/EU cap the register allocator must respect.
constexpr int LDS_PAD_FLOATS = 9216;

constexpr float C1f = 6.5025f;    // (0.01*255)^2
constexpr float C2f = 58.5225f;   // (0.03*255)^2
constexpr float INV49 = 1.0f / 49.0f;

__device__ __forceinline__ float bperm(int addr, float v) {
  return __int_as_float(__builtin_amdgcn_ds_bpermute(addr, __float_as_int(v)));
}

__global__ __attribute__((amdgpu_flat_work_group_size(256, 256),
                          amdgpu_waves_per_eu(4, 4)))
void ssim_kernel(const float* __restrict__ img1, const float* __restrict__ img2,
                 double* __restrict__ partial) {
  // 36 KiB static LDS: used for the final reduction, sized as the occupancy
  // anchor (see header comment). Runtime-indexed -> cannot be shrunk.
  __shared__ float wsum[LDS_PAD_FLOATS];

  const int t = threadIdx.x;
  const int lane = t & 63;
  const int xw = blockIdx.x * TW + (t >> 6) * WCOLS;  // wave col base
  const int y0 = blockIdx.y * TH;
  const size_t ib = (size_t)blockIdx.z * (size_t)(H_IN * W_IN);
  const float* __restrict__ p1 = img1 + ib;
  const float* __restrict__ p2 = img2 + ib;

  // gcol is always even (xw even, 2*lane even) -> the W_IN-2 clamp can only
  // hit non-productive/halo-irrelevant lanes (parity argument: the last
  // productive window, col 1913, is always a c1, whose c0+7 halo float is
  // lane+3's .y at cols (1918,1919) -> unclamped).
  const int gcol = min(xw + 2 * lane, W_IN - 2);  // clamped, 8B-aligned
  const int up1 = ((lane + 1) & 63) << 2;         // bpermute byte addrs
  const int up2 = ((lane + 2) & 63) << 2;
  const int up3 = ((lane + 3) & 63) << 2;
  const bool lv = lane < 61;
  const bool m0 = lv && (xw + 2 * lane + 0 < WOUT);
  const bool m1 = lv && (xw + 2 * lane + 1 < WOUT);

  // thread-private rowsum ring: 5 quantities x 2 cols x 7 slots (named)
#define DECLR(Q, C)                                                          \
  float R##Q##_##C##_0 = 0.f, R##Q##_##C##_1 = 0.f, R##Q##_##C##_2 = 0.f,    \
        R##Q##_##C##_3 = 0.f, R##Q##_##C##_4 = 0.f, R##Q##_##C##_5 = 0.f,    \
        R##Q##_##C##_6 = 0.f;
  DECLR(1, 0) DECLR(1, 1)
  DECLR(2, 0) DECLR(2, 1)
  DECLR(3, 0) DECLR(3, 1)   // 3 = a*a
  DECLR(4, 0) DECLR(4, 1)   // 4 = b*b
  DECLR(5, 0) DECLR(5, 1)   // 5 = a*b
#undef DECLR
#define DECLV(Q) float V##Q##_0 = 0.f, V##Q##_1 = 0.f;
  DECLV(1) DECLV(2) DECLV(3) DECLV(4) DECLV(5)
#undef DECLV

  float accv = 0.f;

  // prologue: row y0 -> A registers (y0 <= 1065, no clamp needed)
  float2 Aa = *(const float2*)(p1 + (size_t)y0 * W_IN + gcol);
  float2 Ab = *(const float2*)(p2 + (size_t)y0 * W_IN + gcol);
  float2 Ba, Bb;
  int gyn = y0 + 1;   // next input row to load (block-uniform -> SALU)
  int oy = y0;        // output row counter

#define QC(Q, C, J)                                                         \
  { V##Q##_##C += s - R##Q##_##C##_##J; R##Q##_##C##_##J = s; }

#define EPI1(VA, VB, VAA, VBB, VAB, MASK)                                   \
  {                                                                         \
    const float mu1 = (VA) * INV49, mu2 = (VB) * INV49;                     \
    const float mu1s = mu1 * mu1, mu2s = mu2 * mu2, mu12 = mu1 * mu2;       \
    const float sg1 = fmaf((VAA), INV49, -mu1s);                            \
    const float sg2 = fmaf((VBB), INV49, -mu2s);                            \
    const float sg12 = fmaf((VAB), INV49, -mu12);                           \
    const float v1 = fmaf(2.f, sg12, C2f);                                  \
    const float v2 = sg1 + sg2 + C2f;                                       \
    const float num = fmaf(2.f, mu12, C1f) * v1;                            \
    const float den = (mu1s + mu2s + C1f) * v2;                             \
    const float ss = num * __builtin_amdgcn_rcpf(den);                      \
    accv += (MASK) ? ss : 0.f;                                              \
  }

  // One input row k: CA holds row k (both imgs); NA receives row k+1
  // (issued first for latency cover); halo via bpermute; ring-slide; EPI.
  // Window cols for c0: CAa.x(c0) CAa.y(+1) a1x(+2) a1y(+3) a2x(+4)
  //                     a2y(+5) a3x(+6);  c1 slides: -CAa.x +a3y(+7).
#define STEP(J, CAa, CAb, NAa, NAb, DO_EPI)                                 \
  {                                                                         \
    NAa = *(const float2*)(p1 + (size_t)gyn * W_IN + gcol);                 \
    NAb = *(const float2*)(p2 + (size_t)gyn * W_IN + gcol);                 \
    gyn = min(gyn + 1, H_IN - 1);                                           \
    const float a1x = bperm(up1, CAa.x), a1y = bperm(up1, CAa.y);           \
    const float a2x = bperm(up2, CAa.x), a2y = bperm(up2, CAa.y);           \
    const float a3x = bperm(up3, CAa.x), a3y = bperm(up3, CAa.y);           \
    const float b1x = bperm(up1, CAb.x), b1y = bperm(up1, CAb.y);           \
    const float b2x = bperm(up2, CAb.x), b2y = bperm(up2, CAb.y);           \
    const float b3x = bperm(up3, CAb.x), b3y = bperm(up3, CAb.y);           \
    float s;                                                                \
    s = ((CAa.x + CAa.y) + (a1x + a1y)) + ((a2x + a2y) + a3x);              \
    QC(1, 0, J)                                                             \
    s = s - CAa.x + a3y;  QC(1, 1, J)                                       \
    s = ((CAb.x + CAb.y) + (b1x + b1y)) + ((b2x + b2y) + b3x);              \
    QC(2, 0, J)                                                             \
    s = s - CAb.x + b3y;  QC(2, 1, J)                                       \
    s = CAa.x * CAa.x;                                                      \
    s = fmaf(CAa.y, CAa.y, s); s = fmaf(a1x, a1x, s);                       \
    s = fmaf(a1y, a1y, s); s = fmaf(a2x, a2x, s);                           \
    s = fmaf(a2y, a2y, s); s = fmaf(a3x, a3x, s);                           \
    QC(3, 0, J)                                                             \
    s = fmaf(-CAa.x, CAa.x, fmaf(a3y, a3y, s));  QC(3, 1, J)                \
    s = CAb.x * CAb.x;                                                      \
    s = fmaf(CAb.y, CAb.y, s); s = fmaf(b1x, b1x, s);                       \
    s = fmaf(b1y, b1y, s); s = fmaf(b2x, b2x, s);                           \
    s = fmaf(b2y, b2y, s); s = fmaf(b3x, b3x, s);                           \
    QC(4, 0, J)                                                             \
    s = fmaf(-CAb.x, CAb.x, fmaf(b3y, b3y, s));  QC(4, 1, J)                \
    s = CAa.x * CAb.x;                                                      \
    s = fmaf(CAa.y, CAb.y, s); s = fmaf(a1x, b1x, s);                       \
    s = fmaf(a1y, b1y, s); s = fmaf(a2x, b2x, s);                           \
    s = fmaf(a2y, b2y, s); s = fmaf(a3x, b3x, s);                           \
    QC(5, 0, J)                                                             \
    s = fmaf(-CAa.x, CAb.x, fmaf(a3y, b3y, s));  QC(5, 1, J)                \
    if (DO_EPI) {                                                           \
      if (oy < HOUT) {                                                      \
        EPI1(V1_0, V2_0, V3_0, V4_0, V5_0, m0)                              \
        EPI1(V1_1, V2_1, V3_1, V4_1, V5_1, m1)                              \
      }                                                                     \
      ++oy;                                                                 \
    }                                                                       \
  }

  // warm-up group: rows 0..6 (row k consumed from A if k even, B if odd)
  STEP(0, Aa, Ab, Ba, Bb, false)
  STEP(1, Ba, Bb, Aa, Ab, false)
  STEP(2, Aa, Ab, Ba, Bb, false)
  STEP(3, Ba, Bb, Aa, Ab, false)
  STEP(4, Aa, Ab, Ba, Bb, false)
  STEP(5, Ba, Bb, Aa, Ab, false)
  STEP(6, Aa, Ab, Ba, Bb, true)
  // 5 x (odd-start group + even-start group): rows 7..76
  for (int gp = 0; gp < 5; ++gp) {
    STEP(0, Ba, Bb, Aa, Ab, true)
    STEP(1, Aa, Ab, Ba, Bb, true)
    STEP(2, Ba, Bb, Aa, Ab, true)
    STEP(3, Aa, Ab, Ba, Bb, true)
    STEP(4, Ba, Bb, Aa, Ab, true)
    STEP(5, Aa, Ab, Ba, Bb, true)
    STEP(6, Ba, Bb, Aa, Ab, true)
    STEP(0, Aa, Ab, Ba, Bb, true)
    STEP(1, Ba, Bb, Aa, Ab, true)
    STEP(2, Aa, Ab, Ba, Bb, true)
    STEP(3, Ba, Bb, Aa, Ab, true)
    STEP(4, Aa, Ab, Ba, Bb, true)
    STEP(5, Ba, Bb, Aa, Ab, true)
    STEP(6, Aa, Ab, Ba, Bb, true)
  }
#undef STEP
#undef QC
#undef EPI1

  // block reduction: 64-wide shuffle -> LDS -> one double per block
#pragma unroll
  for (int off = 32; off > 0; off >>= 1) accv += __shfl_down(accv, off);
  if ((t & 63) == 0) wsum[t >> 6] = accv;
  __syncthreads();
  if (t == 0) {
    const int bid = blockIdx.x + NBX * (blockIdx.y + NBY * blockIdx.z);
    partial[bid] = (double)wsum[0] + (double)wsum[1] +
                   (double)wsum[2] + (double)wsum[3];
  }
}

__global__ __launch_bounds__(256)
void finalize_kernel(const double* __restrict__ partial,
                     float* __restrict__ out) {
  const int tid = threadIdx.x;
  double s = 0.0;
  for (int i = tid; i < NBLK; i += 256) s += partial[i];
#pragma unroll
  for (int off = 32; off > 0; off >>= 1) s += __shfl_down(s, off);
  __shared__ double ws[4];
  if ((tid & 63) == 0) ws[tid >> 6] = s;
  __syncthreads();
  if (tid == 0) {
    const double tot = ws[0] + ws[1] + ws[2] + ws[3];
    out[0] = (float)(tot / ((double)NBATCH * (double)HOUT * (double)WOUT));
  }
}

extern "C" void kernel_launch(void* const* d_in, const int* in_sizes, int n_in,
                              void* d_out, int out_size, void* d_ws, size_t ws_size,
                              hipStream_t stream) {
  const float* img1 = (const float*)d_in[0];
  const float* img2 = (const float*)d_in[1];
  // d_in[2] is the uniform 1/49 window -- baked into INV49.
  double* partial = (double*)d_ws;  // NBLK doubles, every slot written
  dim3 grid(NBX, NBY, NBATCH);      // 4 x 16 x 16 = 1024 blocks
  hipLaunchKernelGGL(ssim_kernel, grid, dim3(256), 0, stream, img1, img2,
                     partial);
  hipLaunchKernelGGL(finalize_kernel, dim3(1), dim3(256), 0, stream, partial,
                     (float*)d_out);
}

// Round 5
// 289.300 us; speedup vs baseline: 1.0173x; 1.0133x over previous
//
#include <hip/hip_runtime.h>

// SSIM fused, round 10: design FOR the 64-VGPR allocator (spill-proof).
//  - Rounds 7-9: two compiler builds in the container pool. Good build:
//    VGPR=128, 53 us. Bad build: VGPR=64 + 88 MB scratch spills, 119-138 us.
//    waves_per_eu(4,4), amdgpu_num_vgpr(128), AND a 36 KiB LDS occupancy
//    anchor were ALL ignored by the bad build -> its 64-reg allocation is a
//    fallback, not a heuristic we can steer. Container build is a lottery.
//  - Fix: restructure so live state fits 64 regs on ANY build.
//      * vertical-FIRST: registers hold only running 7-row vertical sums
//        V_q (5 quantities x 2 cols = 10 floats), not 70 rowsums.
//      * the 7-row history is raw pixels only (a,b x 2 cols x 7) and lives
//        in a per-thread LDS ring (28 KiB/block, slot-major => conflict-free
//        ds_*_b64, thread-private => no barriers, unspillable).
//      * horizontal 7-tap moves to the epilogue over V via pair sums:
//        H_q = Vq0+Vq1; h0 = H + H(+1) + H(+2) + V0(+3);
//        h1 = V1 + H(+1) + H(+2) + H(+3). 4 bpermutes + ~6 adds per q.
//    Per step: ~85 VALU (was ~100), 20 bpermute + 4 ds (was 12 bpermute).
//    Loop-carried regs ~30, peak ~60. Geometry/masks/prefetch unchanged.
// Geometry: 16 x 1 x 1080 x 1920 fp32; VALID 7x7 -> 16 x 1074 x 1914.

constexpr int W_IN = 1920, H_IN = 1080;
constexpr int WOUT = W_IN - 6;    // 1914
constexpr int HOUT = H_IN - 6;    // 1074
constexpr int NBATCH = 16;
constexpr int WCOLS = 122;        // productive cols per wave (61 lanes x 2)
constexpr int TW = 4 * WCOLS;     // 488 cols per block
constexpr int TH = 71;            // output rows per y-tile (NITER = 77 = 7*11)
constexpr int NBX = 4, NBY = 16;  // 4*488>=1914(+pad), 16*71>=1074
constexpr int NBLK = NBX * NBY * NBATCH;  // 1024 = exactly 4 per CU

constexpr float C1f = 6.5025f;    // (0.01*255)^2
constexpr float C2f = 58.5225f;   // (0.03*255)^2
constexpr float INV49 = 1.0f / 49.0f;

__device__ __forceinline__ float bperm(int addr, float v) {
  return __int_as_float(__builtin_amdgcn_ds_bpermute(addr, __float_as_int(v)));
}

__global__ __attribute__((amdgpu_flat_work_group_size(256, 256),
                          amdgpu_waves_per_eu(4, 4)))
void ssim_kernel(const float* __restrict__ img1, const float* __restrict__ img2,
                 double* __restrict__ partial) {
  // Per-thread pixel ring in LDS: [img][slot 0..6][thread] float2.
  // Slot-major: lane i reads base + i*8 -> consecutive 8B/lane, conflict-
  // free b64. Thread-private region -> no __syncthreads ever needed.
  __shared__ float2 ring[2 * 7 * 256];  // 28672 B
  __shared__ float wsum[4];

  const int t = threadIdx.x;
  float2* const rA = ring + t;              // slot J at rA[J*256]
  float2* const rB = ring + 7 * 256 + t;    // slot J at rB[J*256]

  const int lane = t & 63;
  const int xw = blockIdx.x * TW + (t >> 6) * WCOLS;  // wave col base
  const int y0 = blockIdx.y * TH;
  const size_t ib = (size_t)blockIdx.z * (size_t)(H_IN * W_IN);
  const float* __restrict__ p1 = img1 + ib;
  const float* __restrict__ p2 = img2 + ib;

  // gcol always even; clamp only hits halo-irrelevant lanes (see r6 notes).
  const int gcol = min(xw + 2 * lane, W_IN - 2);  // clamped, 8B-aligned
  const int up1 = ((lane + 1) & 63) << 2;         // bpermute byte addrs
  const int up2 = ((lane + 2) & 63) << 2;
  const int up3 = ((lane + 3) & 63) << 2;
  const bool lv = lane < 61;
  const bool m0 = lv && (xw + 2 * lane + 0 < WOUT);
  const bool m1 = lv && (xw + 2 * lane + 1 < WOUT);

  // zero the pixel ring (own slots only -> wave-ordered, no barrier)
  const float2 z2 = make_float2(0.f, 0.f);
#pragma unroll
  for (int j = 0; j < 7; ++j) { rA[j * 256] = z2; rB[j * 256] = z2; }

  // running vertical sums: 5 quantities x 2 cols
  float V1_0 = 0.f, V1_1 = 0.f;   // sum a
  float V2_0 = 0.f, V2_1 = 0.f;   // sum b
  float V3_0 = 0.f, V3_1 = 0.f;   // sum a*a
  float V4_0 = 0.f, V4_1 = 0.f;   // sum b*b
  float V5_0 = 0.f, V5_1 = 0.f;   // sum a*b

  float accv = 0.f;

  // prologue: row y0 -> A registers (y0 <= 1065, no clamp needed)
  float2 Aa = *(const float2*)(p1 + (size_t)y0 * W_IN + gcol);
  float2 Ab = *(const float2*)(p2 + (size_t)y0 * W_IN + gcol);
  float2 Ba, Bb;
  int gyn = y0 + 1;   // next input row to load (block-uniform -> SALU)
  int oy = y0;        // output row counter

#define EPI1(VA, VB, VAA, VBB, VAB, MASK)                                   \
  {                                                                         \
    const float mu1 = (VA) * INV49, mu2 = (VB) * INV49;                     \
    const float mu1s = mu1 * mu1, mu2s = mu2 * mu2, mu12 = mu1 * mu2;       \
    const float sg1 = fmaf((VAA), INV49, -mu1s);                            \
    const float sg2 = fmaf((VBB), INV49, -mu2s);                            \
    const float sg12 = fmaf((VAB), INV49, -mu12);                           \
    const float v1 = fmaf(2.f, sg12, C2f);                                  \
    const float v2 = sg1 + sg2 + C2f;                                       \
    const float num = fmaf(2.f, mu12, C1f) * v1;                            \
    const float den = (mu1s + mu2s + C1f) * v2;                             \
    const float ss = num * __builtin_amdgcn_rcpf(den);                      \
    accv += (MASK) ? ss : 0.f;                                              \
  }

  // horizontal 7-tap for quantity Q via pair sums + 4 bpermutes:
  // own cols (c0,c1); +1 -> (c0+2,c0+3); +2 -> (c0+4,c0+5); +3 -> (c0+6,c0+7)
  // h0 = sum cols c0..c0+6 ; h1 = sum cols c1..c1+6
#define HQ(Q)                                                               \
    const float s1_##Q = bperm(up1, H##Q);                                  \
    const float s2_##Q = bperm(up2, H##Q);                                  \
    const float s3_##Q = bperm(up3, H##Q);                                  \
    const float f3_##Q = bperm(up3, V##Q##_0);                              \
    const float sh_##Q = s1_##Q + s2_##Q;                                   \
    const float h0_##Q = (H##Q + sh_##Q) + f3_##Q;                          \
    const float h1_##Q = (V##Q##_1 + sh_##Q) + s3_##Q;

  // One input row k: CA holds row k (loaded last step); NA receives row k+1
  // (issued first for latency cover). Ring slot J holds row k-7's pixels:
  // read old, write new (same addr, per-wave DS order => RAW/WAR safe).
#define STEP(J, CAa, CAb, NAa, NAb, DO_EPI)                                 \
  {                                                                         \
    NAa = *(const float2*)(p1 + (size_t)gyn * W_IN + gcol);                 \
    NAb = *(const float2*)(p2 + (size_t)gyn * W_IN + gcol);                 \
    gyn = min(gyn + 1, H_IN - 1);                                           \
    const float2 oa = rA[(J) * 256];                                        \
    const float2 ob = rB[(J) * 256];                                        \
    rA[(J) * 256] = CAa;                                                    \
    rB[(J) * 256] = CAb;                                                    \
    V1_0 = (V1_0 + CAa.x) - oa.x;  V1_1 = (V1_1 + CAa.y) - oa.y;            \
    V2_0 = (V2_0 + CAb.x) - ob.x;  V2_1 = (V2_1 + CAb.y) - ob.y;            \
    V3_0 = fmaf(CAa.x, CAa.x, V3_0); V3_0 = fmaf(-oa.x, oa.x, V3_0);        \
    V3_1 = fmaf(CAa.y, CAa.y, V3_1); V3_1 = fmaf(-oa.y, oa.y, V3_1);        \
    V4_0 = fmaf(CAb.x, CAb.x, V4_0); V4_0 = fmaf(-ob.x, ob.x, V4_0);        \
    V4_1 = fmaf(CAb.y, CAb.y, V4_1); V4_1 = fmaf(-ob.y, ob.y, V4_1);        \
    V5_0 = fmaf(CAa.x, CAb.x, V5_0); V5_0 = fmaf(-oa.x, ob.x, V5_0);        \
    V5_1 = fmaf(CAa.y, CAb.y, V5_1); V5_1 = fmaf(-oa.y, ob.y, V5_1);        \
    if (DO_EPI) {                                                           \
      if (oy < HOUT) {                                                      \
        const float H1 = V1_0 + V1_1;                                       \
        const float H2 = V2_0 + V2_1;                                       \
        const float H3 = V3_0 + V3_1;                                       \
        const float H4 = V4_0 + V4_1;                                       \
        const float H5 = V5_0 + V5_1;                                       \
        HQ(1) HQ(2) HQ(3) HQ(4) HQ(5)                                       \
        EPI1(h0_1, h0_2, h0_3, h0_4, h0_5, m0)                              \
        EPI1(h1_1, h1_2, h1_3, h1_4, h1_5, m1)                              \
      }                                                                     \
      ++oy;                                                                 \
    }                                                                       \
  }

  // warm-up group: rows 0..6 (row k consumed from A if k even, B if odd)
  STEP(0, Aa, Ab, Ba, Bb, false)
  STEP(1, Ba, Bb, Aa, Ab, false)
  STEP(2, Aa, Ab, Ba, Bb, false)
  STEP(3, Ba, Bb, Aa, Ab, false)
  STEP(4, Aa, Ab, Ba, Bb, false)
  STEP(5, Ba, Bb, Aa, Ab, false)
  STEP(6, Aa, Ab, Ba, Bb, true)
  // 5 x (odd-start group + even-start group): rows 7..76
  for (int gp = 0; gp < 5; ++gp) {
    STEP(0, Ba, Bb, Aa, Ab, true)
    STEP(1, Aa, Ab, Ba, Bb, true)
    STEP(2, Ba, Bb, Aa, Ab, true)
    STEP(3, Aa, Ab, Ba, Bb, true)
    STEP(4, Ba, Bb, Aa, Ab, true)
    STEP(5, Aa, Ab, Ba, Bb, true)
    STEP(6, Ba, Bb, Aa, Ab, true)
    STEP(0, Aa, Ab, Ba, Bb, true)
    STEP(1, Ba, Bb, Aa, Ab, true)
    STEP(2, Aa, Ab, Ba, Bb, true)
    STEP(3, Ba, Bb, Aa, Ab, true)
    STEP(4, Aa, Ab, Ba, Bb, true)
    STEP(5, Ba, Bb, Aa, Ab, true)
    STEP(6, Aa, Ab, Ba, Bb, true)
  }
#undef STEP
#undef HQ
#undef EPI1

  // block reduction: 64-wide shuffle -> LDS -> one double per block
#pragma unroll
  for (int off = 32; off > 0; off >>= 1) accv += __shfl_down(accv, off);
  if ((t & 63) == 0) wsum[t >> 6] = accv;
  __syncthreads();
  if (t == 0) {
    const int bid = blockIdx.x + NBX * (blockIdx.y + NBY * blockIdx.z);
    partial[bid] = (double)wsum[0] + (double)wsum[1] +
                   (double)wsum[2] + (double)wsum[3];
  }
}

__global__ __launch_bounds__(256)
void finalize_kernel(const double* __restrict__ partial,
                     float* __restrict__ out) {
  const int tid = threadIdx.x;
  double s = 0.0;
  for (int i = tid; i < NBLK; i += 256) s += partial[i];
#pragma unroll
  for (int off = 32; off > 0; off >>= 1) s += __shfl_down(s, off);
  __shared__ double ws[4];
  if ((tid & 63) == 0) ws[tid >> 6] = s;
  __syncthreads();
  if (tid == 0) {
    const double tot = ws[0] + ws[1] + ws[2] + ws[3];
    out[0] = (float)(tot / ((double)NBATCH * (double)HOUT * (double)WOUT));
  }
}

extern "C" void kernel_launch(void* const* d_in, const int* in_sizes, int n_in,
                              void* d_out, int out_size, void* d_ws, size_t ws_size,
                              hipStream_t stream) {
  const float* img1 = (const float*)d_in[0];
  const float* img2 = (const float*)d_in[1];
  // d_in[2] is the uniform 1/49 window -- baked into INV49.
  double* partial = (double*)d_ws;  // NBLK doubles, every slot written
  dim3 grid(NBX, NBY, NBATCH);      // 4 x 16 x 16 = 1024 blocks
  hipLaunchKernelGGL(ssim_kernel, grid, dim3(256), 0, stream, img1, img2,
                     partial);
  hipLaunchKernelGGL(finalize_kernel, dim3(1), dim3(256), 0, stream, partial,
                     (float*)d_out);
}